// Round 11
// baseline (408.834 us; speedup 1.0000x reference)
//
#include <hip/hip_runtime.h>
#include <hip/hip_bf16.h>
#include <cstddef>

typedef unsigned int  u32;
typedef unsigned short u16;
typedef __attribute__((ext_vector_type(8))) short short8;
typedef __attribute__((ext_vector_type(4))) float f32x4;
typedef __attribute__((ext_vector_type(2))) float f32x2;

#define DV 128
#define DH 128
#define DE 16
#define DO 128

// ---------- bf16 helpers (bit tricks, RNE) ----------
__device__ inline float bf_lo(u32 u){ return __uint_as_float(u << 16); }
__device__ inline float bf_hi(u32 u){ return __uint_as_float(u & 0xFFFF0000u); }
__device__ inline u32 fpack2(float a, float b){
  u32 ua = __float_as_uint(a), ub = __float_as_uint(b);
  ua += 0x7FFFu + ((ua >> 16) & 1u);
  ub += 0x7FFFu + ((ub >> 16) & 1u);
  return (ua >> 16) | (ub & 0xFFFF0000u);
}
__device__ inline u16 f2bf(float a){
  u32 ua = __float_as_uint(a); ua += 0x7FFFu + ((ua >> 16) & 1u); return (u16)(ua >> 16);
}

// ---------- fp8 (OCP e4m3) helpers: 4 channels per u32 ----------
__device__ inline void acc_fp8v(u32 s, f32x2& lo, f32x2& hi){
  lo += __builtin_amdgcn_cvt_pk_f32_fp8((int)s, false);
  hi += __builtin_amdgcn_cvt_pk_f32_fp8((int)s, true);
}
__device__ inline u32 pack_fp8(float a0, float a1, float a2, float a3){
  int o = __builtin_amdgcn_cvt_pk_fp8_f32(a0, a1, 0, false);
  o = __builtin_amdgcn_cvt_pk_fp8_f32(a2, a3, o, true);
  return (u32)o;
}

// ---------- init: zero cnt/poolp/zrows (ce prefill rides under k_count) ----------
__global__ void k_init(int* cnt, float* poolp, u32* xws_zrow, u32* h_zrow, int n, int pn){
  int v = blockIdx.x * blockDim.x + threadIdx.x;
  if (v < n) cnt[v] = 0;
  if (v < pn) poolp[v] = 0.f;
  if (v < 32){ xws_zrow[v] = 0u; h_zrow[v] = 0u; }
}

// count + per-edge rank (atomic-throughput-bound, ~68us floor). Streaming riders
// nearly free under the atomic latency (r2/r3 A/B): ea->bf16 table, ce pad-prefill.
__global__ void k_count(const int* dst, const float* edge_attr, int* cnt, int* rank,
                        u32* ea_pack, int2* ce, int e2, int cefill, int nmark){
  int j = blockIdx.x * blockDim.x + threadIdx.x;
  int tot = gridDim.x * blockDim.x;
  if (j < e2){
    rank[j] = atomicAdd(&cnt[dst[j]], 1);
    float4 f0 = *(const float4*)(edge_attr + (size_t)j * 8);
    float4 f1 = *(const float4*)(edge_attr + (size_t)j * 8 + 4);
    uint4 o;
    o.x = fpack2(f0.x, f0.y); o.y = fpack2(f0.z, f0.w);
    o.z = fpack2(f1.x, f1.y); o.w = fpack2(f1.z, f1.w);
    *(uint4*)(ea_pack + (size_t)j * 4) = o;
  }
  int2 pd = make_int2(nmark, 0);
  for (int i = j; i < cefill; i += tot) ce[i] = pd;
}

// scan of PADDED counts: pc = (cnt+7)&~7
__global__ __launch_bounds__(256) void k_scan1(const int* cnt, int* partial, int* bsums, int n){
  __shared__ int lds[256];
  int t = threadIdx.x;
  int base = blockIdx.x * 1024 + t * 4;
  int v0=0,v1=0,v2=0,v3=0;
  if (base + 3 < n){ int4 q = *(const int4*)(cnt + base); v0=q.x; v1=q.y; v2=q.z; v3=q.w; }
  else {
    if (base + 0 < n) v0 = cnt[base];
    if (base + 1 < n) v1 = cnt[base+1];
    if (base + 2 < n) v2 = cnt[base+2];
  }
  v0 = (v0 + 7) & ~7; v1 = (v1 + 7) & ~7; v2 = (v2 + 7) & ~7; v3 = (v3 + 7) & ~7;
  v1 += v0; v2 += v1; v3 += v2;
  lds[t] = v3; __syncthreads();
  for (int off = 1; off < 256; off <<= 1){
    int x = (t >= off) ? lds[t - off] : 0;
    __syncthreads();
    lds[t] += x;
    __syncthreads();
  }
  int add = (t > 0) ? lds[t - 1] : 0;
  if (base + 3 < n){
    int4 q; q.x = v0+add; q.y = v1+add; q.z = v2+add; q.w = v3+add;
    *(int4*)(partial + base) = q;
  } else {
    if (base + 0 < n) partial[base]   = v0 + add;
    if (base + 1 < n) partial[base+1] = v1 + add;
    if (base + 2 < n) partial[base+2] = v2 + add;
  }
  if (t == 255) bsums[blockIdx.x] = lds[255];
}

// fused: (a) blocks [0,NB): inline bsums scan + row_ptr + dinv/degf + graph starts;
// (b) blocks [NB,NB+80): wcombo weight fold (fp32 Wfull, r9 form).
__global__ __launch_bounds__(256) void k_scan3w(const int* partial, const int* bsums, int nb,
                                                int* row_ptr, const int* cnt,
                                                float* dinv, float* degf,
                                                const int* batch, int* startg, int n, int g, int NB,
                                                const float* W_lin, const float* b_lin,
                                                const float* W_le, const float* b_le, float* Wfull){
  int bid = blockIdx.x;
  int t = threadIdx.x;
  if (bid >= NB){
    int r = (bid - NB) * 2 + (t >> 7), c = t & 127;
    if (r < DH){
      Wfull[r * DH + c] = W_lin[r * DH + c];
    } else if (r < DH + DE){
      int i = r - DH;
      float acc = 0.f;
      #pragma unroll 8
      for (int k = 0; k < DH; k += 4){
        float4 wl = *(const float4*)(W_le + i * DH + k);
        acc += wl.x * W_lin[(size_t)(DH + k    ) * DH + c];
        acc += wl.y * W_lin[(size_t)(DH + k + 1) * DH + c];
        acc += wl.z * W_lin[(size_t)(DH + k + 2) * DH + c];
        acc += wl.w * W_lin[(size_t)(DH + k + 3) * DH + c];
      }
      Wfull[r * DH + c] = acc;
    } else if (r == 144){
      float acc = b_lin[c];
      #pragma unroll 8
      for (int k = 0; k < DH; k += 4){
        float4 bl = *(const float4*)(b_le + k);
        acc += bl.x * W_lin[(size_t)(DH + k    ) * DH + c];
        acc += bl.y * W_lin[(size_t)(DH + k + 1) * DH + c];
        acc += bl.z * W_lin[(size_t)(DH + k + 2) * DH + c];
        acc += bl.w * W_lin[(size_t)(DH + k + 3) * DH + c];
      }
      Wfull[r * DH + c] = acc;
    } else if (r < 160){
      Wfull[r * DH + c] = 0.f;
    }
    return;
  }
  __shared__ int lds[128];
  if (t < 128) lds[t] = (t < nb) ? bsums[t] : 0;
  __syncthreads();
  for (int off = 1; off < 128; off <<= 1){
    int x = (t >= off && t < 128) ? lds[t - off] : 0;
    __syncthreads();
    if (t < 128) lds[t] += x;
    __syncthreads();
  }
  int i = bid * 256 + t;
  if (i < n){
    int chunk = i >> 10;
    int add = (chunk > 0) ? lds[chunk - 1] : 0;
    row_ptr[i + 1] = partial[i] + add;
    if (i == 0) row_ptr[0] = 0;
    float c = (float)(cnt[i] + 1);
    dinv[i] = rsqrtf(c);
    degf[i] = c;
    int b = batch[i];
    int prev = (i == 0) ? -1 : batch[i - 1];
    for (int q = prev + 1; q <= b; ++q) startg[q] = i;
    if (i == n - 1){ for (int q = b + 1; q <= g; ++q) startg[q] = n; }
  }
}

// ---------- fused scatter + gemm1 (r5->r6 proved gemm1 hides under scatter) ----------
__global__ __launch_bounds__(256) void k_scatter_g1(const int* src, const int* dst, const int* rank,
                                                    const int* row_ptr, int2* ce, int e2, int SB,
                                                    const float* x, const float* W,
                                                    const float* dinv, u32* xws8, int M){
  __shared__ u16 lds_u[64 * 136];   // 17408 B
  int bid = blockIdx.x;
  int tid = threadIdx.x;
  if (bid < SB){
    int j = bid * 256 + tid;
    if (j < e2){
      int d = dst[j];
      int pos = row_ptr[d] + rank[j];
      ce[pos] = make_int2(src[j] << 5, j >> 1);
    }
    return;
  }
  int row0 = (bid - SB) * 64;
  u16* Wt = lds_u;              // per-slice [128][40]
  u16* At = lds_u + 128 * 40;   // per-slice [64][40]
  int l = tid & 63, w = tid >> 6;
  int m = l & 15, quad = l >> 4;
  f32x4 acc[8];
  #pragma unroll
  for (int ct = 0; ct < 8; ++ct) acc[ct] = (f32x4){0.f, 0.f, 0.f, 0.f};
  for (int ks = 0; ks < DV; ks += 32){
    __syncthreads();
    {
      int c = tid & 127, hh = tid >> 7;
      #pragma unroll
      for (int g2 = 0; g2 < 2; ++g2){
        int k0 = hh * 16 + g2 * 8;
        const float* Wp = W + (size_t)(ks + k0) * 128 + c;
        float w0 = Wp[0*128], w1 = Wp[1*128], w2 = Wp[2*128], w3 = Wp[3*128];
        float w4 = Wp[4*128], w5 = Wp[5*128], w6 = Wp[6*128], w7 = Wp[7*128];
        uint4 pk;
        pk.x = fpack2(w0, w1); pk.y = fpack2(w2, w3);
        pk.z = fpack2(w4, w5); pk.w = fpack2(w6, w7);
        *(uint4*)&Wt[c * 40 + k0] = pk;
      }
    }
    {
      int r = tid >> 2, ch = tid & 3;
      int gr = row0 + r; if (gr > M - 1) gr = M - 1;
      const float* A = x + (size_t)gr * DV + ks + ch * 8;
      float4 q0 = *(const float4*)A;
      float4 q1 = *(const float4*)(A + 4);
      uint4 pk;
      pk.x = fpack2(q0.x, q0.y); pk.y = fpack2(q0.z, q0.w);
      pk.z = fpack2(q1.x, q1.y); pk.w = fpack2(q1.z, q1.w);
      *(uint4*)&At[r * 40 + ch * 8] = pk;
    }
    __syncthreads();
    short8 av = *(const short8*)&At[(w * 16 + m) * 40 + quad * 8];
    #pragma unroll
    for (int ct = 0; ct < 8; ++ct){
      short8 bv = *(const short8*)&Wt[(ct * 16 + m) * 40 + quad * 8];
      acc[ct] = __builtin_amdgcn_mfma_f32_16x16x32_bf16(av, bv, acc[ct], 0, 0, 0);
    }
  }
  __syncthreads();
  u16* Ct = lds_u;
  float sc[4];
  #pragma unroll
  for (int r = 0; r < 4; ++r){
    int gr = row0 + w * 16 + quad * 4 + r;
    sc[r] = dinv[gr < M ? gr : (M - 1)];
  }
  #pragma unroll
  for (int ct = 0; ct < 8; ++ct){
    #pragma unroll
    for (int r = 0; r < 4; ++r){
      float vv = acc[ct][r] * sc[r];
      Ct[(w * 16 + quad * 4 + r) * 136 + ct * 16 + m] = f2bf(vv);
    }
  }
  __syncthreads();
  for (int idx = tid; idx < 64 * 16; idx += 256){
    int r = idx >> 4, c8 = idx & 15;
    int gr = row0 + r;
    if (gr < M){
      uint4 qv = *(const uint4*)&Ct[r * 136 + c8 * 8];
      uint2 ov;
      ov.x = (u32)__builtin_amdgcn_cvt_pk_fp8_f32(bf_lo(qv.y), bf_hi(qv.y),
             __builtin_amdgcn_cvt_pk_fp8_f32(bf_lo(qv.x), bf_hi(qv.x), 0, false), true);
      ov.y = (u32)__builtin_amdgcn_cvt_pk_fp8_f32(bf_lo(qv.w), bf_hi(qv.w),
             __builtin_amdgcn_cvt_pk_fp8_f32(bf_lo(qv.z), bf_hi(qv.z), 0, false), true);
      *(uint2*)(xws8 + (size_t)gr * 32 + c8 * 2) = ov;
    }
  }
}

// ---------- phase 1: fp8 table, 2 nodes/wave, depth-2 pipeline ----------
__global__ __launch_bounds__(256) void k_phase1(const u32* xws8, const int* row_ptr, const int2* ce,
                                                const float* dinv, const float* b_gcn, u32* h8, int n){
  int lane = threadIdx.x & 63;
  int ln = lane & 31;
  int v = blockIdx.x * 8 + ((threadIdx.x >> 6) << 1) + (lane >> 5);
  if (v >= n) return;
  u32 sp = xws8[(size_t)v * 32 + ln];
  f32x2 aLo = (f32x2){0.f, 0.f}, aHi = (f32x2){0.f, 0.f};
  acc_fp8v(sp, aLo, aHi);
  int e0 = row_ptr[v], e1 = row_ptr[v + 1];
  int B = (e1 - e0) >> 3;
  const int4* cp = (const int4*)(ce + e0);
  u32 q0=0,q1=0,q2=0,q3=0,q4=0,q5=0,q6=0,q7=0;
  u32 r0=0,r1=0,r2=0,r3=0,r4=0,r5=0,r6=0,r7=0;
  if (B > 0){
    int4 A = cp[0], Bb = cp[1], C = cp[2], D = cp[3];
    q0 = xws8[A.x + ln]; q1 = xws8[A.z + ln];
    q2 = xws8[Bb.x + ln]; q3 = xws8[Bb.z + ln];
    q4 = xws8[C.x + ln]; q5 = xws8[C.z + ln];
    q6 = xws8[D.x + ln]; q7 = xws8[D.z + ln];
  }
  if (B > 1){
    int4 A = cp[4], Bb = cp[5], C = cp[6], D = cp[7];
    r0 = xws8[A.x + ln]; r1 = xws8[A.z + ln];
    r2 = xws8[Bb.x + ln]; r3 = xws8[Bb.z + ln];
    r4 = xws8[C.x + ln]; r5 = xws8[C.z + ln];
    r6 = xws8[D.x + ln]; r7 = xws8[D.z + ln];
  }
  for (int k = 0; k + 2 < B; ++k){
    const int4* cpp = cp + (size_t)(k + 2) * 4;
    int4 A = cpp[0], Bb = cpp[1], C = cpp[2], D = cpp[3];
    u32 p0 = xws8[A.x + ln], p1 = xws8[A.z + ln];
    u32 p2 = xws8[Bb.x + ln], p3 = xws8[Bb.z + ln];
    u32 p4 = xws8[C.x + ln], p5 = xws8[C.z + ln];
    u32 p6 = xws8[D.x + ln], p7 = xws8[D.z + ln];
    acc_fp8v(q0, aLo, aHi); acc_fp8v(q1, aLo, aHi);
    acc_fp8v(q2, aLo, aHi); acc_fp8v(q3, aLo, aHi);
    acc_fp8v(q4, aLo, aHi); acc_fp8v(q5, aLo, aHi);
    acc_fp8v(q6, aLo, aHi); acc_fp8v(q7, aLo, aHi);
    q0=r0; q1=r1; q2=r2; q3=r3; q4=r4; q5=r5; q6=r6; q7=r7;
    r0=p0; r1=p1; r2=p2; r3=p3; r4=p4; r5=p5; r6=p6; r7=p7;
  }
  if (B > 1){
    acc_fp8v(q0, aLo, aHi); acc_fp8v(q1, aLo, aHi);
    acc_fp8v(q2, aLo, aHi); acc_fp8v(q3, aLo, aHi);
    acc_fp8v(q4, aLo, aHi); acc_fp8v(q5, aLo, aHi);
    acc_fp8v(q6, aLo, aHi); acc_fp8v(q7, aLo, aHi);
    q0=r0; q1=r1; q2=r2; q3=r3; q4=r4; q5=r5; q6=r6; q7=r7;
  }
  if (B > 0){
    acc_fp8v(q0, aLo, aHi); acc_fp8v(q1, aLo, aHi);
    acc_fp8v(q2, aLo, aHi); acc_fp8v(q3, aLo, aHi);
    acc_fp8v(q4, aLo, aHi); acc_fp8v(q5, aLo, aHi);
    acc_fp8v(q6, aLo, aHi); acc_fp8v(q7, aLo, aHi);
  }
  float dv = dinv[v];
  float4 bg = *(const float4*)(b_gcn + ln * 4);
  float a0 = fmaxf(fmaf(dv, aLo.x, bg.x), 0.f);
  float a1 = fmaxf(fmaf(dv, aLo.y, bg.y), 0.f);
  float a2 = fmaxf(fmaf(dv, aHi.x, bg.z), 0.f);
  float a3 = fmaxf(fmaf(dv, aHi.y, bg.w), 0.f);
  h8[(size_t)v * 32 + ln] = pack_fp8(a0, a1, a2, a3);
}

// ---------- FUSED phase2 + gemm2 + pool, DEPTH-2 gather pipeline ----------
// r9 measured: fused gather runs at 1.9 TB/s vs 3.2 standalone — TLP halved
// (8 waves/CU achieved) with per-wave depth still 8. Fix: keep TWO 8-edge
// blocks of h8 gathers + ea values in flight per wave (depth-2, 16+8
// outstanding loads). Block consume order preserved -> bit-identical.
// At2 stride 174 (odd-dword: conflict-free MFMA reads; r10 proved safe).
__global__ __launch_bounds__(256) void k_p2gemm(const u32* h8, const int* row_ptr, const int2* ce,
                                                const u16* ea_bf, const float* degf,
                                                const float* W, int n,
                                                const int* batchp, float* poolp){
  __shared__ u16 At2[64 * 174];      // full A2 tile (22272 B)
  __shared__ u16 Wt[128 * 40];       // per-slice W (10240 B); pool scratch later
  int tid = threadIdx.x;
  int lane = tid & 63;
  int ln = lane & 31;
  int half = lane >> 5;
  int row0 = blockIdx.x * 64;
  int ch = ln & 15, grp = ln >> 4;
  int nmark = n << 5;

  // ---- 8 passes: build A2 rows in LDS (depth-2 pipelined gathers) ----
  for (int pass = 0; pass < 8; ++pass){
    int local = pass * 8 + ((tid >> 6) << 1) + half;
    int v = row0 + local;
    u32* rowp = (u32*)&At2[(size_t)local * 174];
    if (v >= n){
      rowp[ln] = 0u; rowp[ln + 32] = 0u;
      if (ln < 16) rowp[ln + 64] = 0u;
      continue;
    }
    u32 sp = h8[(size_t)v * 32 + ln];
    f32x2 aLo = (f32x2){0.f, 0.f}, aHi = (f32x2){0.f, 0.f};
    acc_fp8v(sp, aLo, aHi);
    float es = 0.f;
    int e0 = row_ptr[v], e1 = row_ptr[v + 1];
    int B = (e1 - e0) >> 3;          // exact: rows pad to 8
    const int4* cp = (const int4*)(ce + e0);
    u32 q0=0,q1=0,q2=0,q3=0,q4=0,q5=0,q6=0,q7=0;   // current block h8
    u32 r0=0,r1=0,r2=0,r3=0,r4=0,r5=0,r6=0,r7=0;   // next block h8
    float w0=0.f,w1=0.f,w2=0.f,w3=0.f, m0=0.f,m1=0.f,m2=0.f,m3=0.f;     // current ea
    float wn0=0.f,wn1=0.f,wn2=0.f,wn3=0.f, mn0=0.f,mn1=0.f,mn2=0.f,mn3=0.f; // next ea
    if (B > 0){
      int4 A = cp[0], Bb = cp[1], C = cp[2], D = cp[3];
      q0 = h8[A.x + ln]; q1 = h8[A.z + ln];
      q2 = h8[Bb.x + ln]; q3 = h8[Bb.z + ln];
      q4 = h8[C.x + ln]; q5 = h8[C.z + ln];
      q6 = h8[D.x + ln]; q7 = h8[D.z + ln];
      int s0x = grp ? C.x : A.x, s0e = grp ? C.y : A.y;
      int s1x = grp ? C.z : A.z, s1e = grp ? C.w : A.w;
      int s2x = grp ? D.x : Bb.x, s2e = grp ? D.y : Bb.y;
      int s3x = grp ? D.z : Bb.z, s3e = grp ? D.w : Bb.w;
      w0 = bf_lo((u32)ea_bf[(size_t)s0e * 16 + ch]);
      w1 = bf_lo((u32)ea_bf[(size_t)s1e * 16 + ch]);
      w2 = bf_lo((u32)ea_bf[(size_t)s2e * 16 + ch]);
      w3 = bf_lo((u32)ea_bf[(size_t)s3e * 16 + ch]);
      m0 = (s0x != nmark) ? 1.f : 0.f;
      m1 = (s1x != nmark) ? 1.f : 0.f;
      m2 = (s2x != nmark) ? 1.f : 0.f;
      m3 = (s3x != nmark) ? 1.f : 0.f;
    }
    if (B > 1){
      int4 A = cp[4], Bb = cp[5], C = cp[6], D = cp[7];
      r0 = h8[A.x + ln]; r1 = h8[A.z + ln];
      r2 = h8[Bb.x + ln]; r3 = h8[Bb.z + ln];
      r4 = h8[C.x + ln]; r5 = h8[C.z + ln];
      r6 = h8[D.x + ln]; r7 = h8[D.z + ln];
      int s0x = grp ? C.x : A.x, s0e = grp ? C.y : A.y;
      int s1x = grp ? C.z : A.z, s1e = grp ? C.w : A.w;
      int s2x = grp ? D.x : Bb.x, s2e = grp ? D.y : Bb.y;
      int s3x = grp ? D.z : Bb.z, s3e = grp ? D.w : Bb.w;
      wn0 = bf_lo((u32)ea_bf[(size_t)s0e * 16 + ch]);
      wn1 = bf_lo((u32)ea_bf[(size_t)s1e * 16 + ch]);
      wn2 = bf_lo((u32)ea_bf[(size_t)s2e * 16 + ch]);
      wn3 = bf_lo((u32)ea_bf[(size_t)s3e * 16 + ch]);
      mn0 = (s0x != nmark) ? 1.f : 0.f;
      mn1 = (s1x != nmark) ? 1.f : 0.f;
      mn2 = (s2x != nmark) ? 1.f : 0.f;
      mn3 = (s3x != nmark) ? 1.f : 0.f;
    }
    for (int k = 0; k + 2 < B; ++k){
      const int4* cpp = cp + (size_t)(k + 2) * 4;
      int4 A = cpp[0], Bb = cpp[1], C = cpp[2], D = cpp[3];
      // block k+2: ea loads + masks
      int t0x = grp ? C.x : A.x, t0e = grp ? C.y : A.y;
      int t1x = grp ? C.z : A.z, t1e = grp ? C.w : A.w;
      int t2x = grp ? D.x : Bb.x, t2e = grp ? D.y : Bb.y;
      int t3x = grp ? D.z : Bb.z, t3e = grp ? D.w : Bb.w;
      float u0 = bf_lo((u32)ea_bf[(size_t)t0e * 16 + ch]);
      float u1 = bf_lo((u32)ea_bf[(size_t)t1e * 16 + ch]);
      float u2 = bf_lo((u32)ea_bf[(size_t)t2e * 16 + ch]);
      float u3 = bf_lo((u32)ea_bf[(size_t)t3e * 16 + ch]);
      float n0 = (t0x != nmark) ? 1.f : 0.f;
      float n1 = (t1x != nmark) ? 1.f : 0.f;
      float n2 = (t2x != nmark) ? 1.f : 0.f;
      float n3 = (t3x != nmark) ? 1.f : 0.f;
      // block k+2: h8 gathers
      u32 p0 = h8[A.x + ln], p1 = h8[A.z + ln];
      u32 p2 = h8[Bb.x + ln], p3 = h8[Bb.z + ln];
      u32 p4 = h8[C.x + ln], p5 = h8[C.z + ln];
      u32 p6 = h8[D.x + ln], p7 = h8[D.z + ln];
      // consume block k (loaded two iterations ago)
      acc_fp8v(q0, aLo, aHi); acc_fp8v(q1, aLo, aHi);
      acc_fp8v(q2, aLo, aHi); acc_fp8v(q3, aLo, aHi);
      acc_fp8v(q4, aLo, aHi); acc_fp8v(q5, aLo, aHi);
      acc_fp8v(q6, aLo, aHi); acc_fp8v(q7, aLo, aHi);
      es = fmaf(m0, w0, es);
      es = fmaf(m1, w1, es);
      es = fmaf(m2, w2, es);
      es = fmaf(m3, w3, es);
      q0=r0; q1=r1; q2=r2; q3=r3; q4=r4; q5=r5; q6=r6; q7=r7;
      r0=p0; r1=p1; r2=p2; r3=p3; r4=p4; r5=p5; r6=p6; r7=p7;
      w0=wn0; w1=wn1; w2=wn2; w3=wn3;
      m0=mn0; m1=mn1; m2=mn2; m3=mn3;
      wn0=u0; wn1=u1; wn2=u2; wn3=u3;
      mn0=n0; mn1=n1; mn2=n2; mn3=n3;
    }
    if (B > 1){
      acc_fp8v(q0, aLo, aHi); acc_fp8v(q1, aLo, aHi);
      acc_fp8v(q2, aLo, aHi); acc_fp8v(q3, aLo, aHi);
      acc_fp8v(q4, aLo, aHi); acc_fp8v(q5, aLo, aHi);
      acc_fp8v(q6, aLo, aHi); acc_fp8v(q7, aLo, aHi);
      es = fmaf(m0, w0, es);
      es = fmaf(m1, w1, es);
      es = fmaf(m2, w2, es);
      es = fmaf(m3, w3, es);
      q0=r0; q1=r1; q2=r2; q3=r3; q4=r4; q5=r5; q6=r6; q7=r7;
      w0=wn0; w1=wn1; w2=wn2; w3=wn3;
      m0=mn0; m1=mn1; m2=mn2; m3=mn3;
    }
    if (B > 0){
      acc_fp8v(q0, aLo, aHi); acc_fp8v(q1, aLo, aHi);
      acc_fp8v(q2, aLo, aHi); acc_fp8v(q3, aLo, aHi);
      acc_fp8v(q4, aLo, aHi); acc_fp8v(q5, aLo, aHi);
      acc_fp8v(q6, aLo, aHi); acc_fp8v(q7, aLo, aHi);
      es = fmaf(m0, w0, es);
      es = fmaf(m1, w1, es);
      es = fmaf(m2, w2, es);
      es = fmaf(m3, w3, es);
    }
    es += __shfl_xor(es, 16);
    float c0v = __shfl(es, half * 32 + (ln & 7) * 2);
    float c1v = __shfl(es, half * 32 + (ln & 7) * 2 + 1);
    uint2 o; o.x = fpack2(aLo.x, aLo.y); o.y = fpack2(aHi.x, aHi.y);
    *(uint2*)(rowp + ln * 2) = o;
    if (ln < 8){
      rowp[64 + ln] = fpack2(c0v + 1.0f, c1v + 1.0f);
    } else if (ln < 16){
      rowp[64 + ln] = (ln == 8) ? (u32)f2bf(degf[v]) : 0u;
    }
  }
  __syncthreads();

  // ---- gemm: At2 @ Wfull (5 slices of K=32), Wt LDS-staged (r9 form) ----
  int l = tid & 63, w = tid >> 6;
  int m = l & 15, quad = l >> 4;
  f32x4 acc[8];
  #pragma unroll
  for (int ct = 0; ct < 8; ++ct) acc[ct] = (f32x4){0.f, 0.f, 0.f, 0.f};
  for (int ks = 0; ks < 160; ks += 32){
    __syncthreads();   // previous slice's Wt fully consumed
    {
      int c = tid & 127, hh = tid >> 7;
      #pragma unroll
      for (int g2 = 0; g2 < 2; ++g2){
        int k0 = hh * 16 + g2 * 8;
        const float* Wp = W + (size_t)(ks + k0) * 128 + c;
        float w0 = Wp[0*128], w1 = Wp[1*128], w2 = Wp[2*128], w3 = Wp[3*128];
        float w4 = Wp[4*128], w5 = Wp[5*128], w6 = Wp[6*128], w7 = Wp[7*128];
        uint4 pk;
        pk.x = fpack2(w0, w1); pk.y = fpack2(w2, w3);
        pk.z = fpack2(w4, w5); pk.w = fpack2(w6, w7);
        *(uint4*)&Wt[c * 40 + k0] = pk;
      }
    }
    __syncthreads();
    short8 av = *(const short8*)&At2[(w * 16 + m) * 174 + ks + quad * 8];
    #pragma unroll
    for (int ct = 0; ct < 8; ++ct){
      short8 bv = *(const short8*)&Wt[(ct * 16 + m) * 40 + quad * 8];
      acc[ct] = __builtin_amdgcn_mfma_f32_16x16x32_bf16(av, bv, acc[ct], 0, 0, 0);
    }
  }
  __syncthreads();   // done with Wt — reuse as pool scratch

  // ---- fused mean-pool epilogue (identical reduction to r9) ----
  float* ps = (float*)Wt;
  int rbase = w * 16 + quad * 4;
  int g0 = batchp[row0];
  int glast = batchp[(row0 + 63 < n) ? (row0 + 63) : (n - 1)];
  if (g0 == glast){
    #pragma unroll
    for (int ct = 0; ct < 8; ++ct){
      float s = 0.f;
      #pragma unroll
      for (int r = 0; r < 4; ++r){
        float vv = fmaxf(acc[ct][r], 0.f);
        if (row0 + rbase + r < n) s += vv;
      }
      s += __shfl_xor(s, 16);
      s += __shfl_xor(s, 32);
      if (quad == 0) ps[w * 128 + ct * 16 + m] = s;
    }
    __syncthreads();
    if (tid < 128){
      float t = ps[tid] + ps[128 + tid] + ps[256 + tid] + ps[384 + tid];
      atomicAdd(&poolp[g0 * DO + tid], t);
    }
  } else {
    #pragma unroll
    for (int ct = 0; ct < 8; ++ct){
      #pragma unroll
      for (int r = 0; r < 4; ++r){
        int row = row0 + rbase + r;
        if (row < n){
          float vv = fmaxf(acc[ct][r], 0.f);
          atomicAdd(&poolp[batchp[row] * DO + ct * 16 + m], vv);
        }
      }
    }
  }
}

// ---------- final: mean + linear ----------
__global__ __launch_bounds__(128) void k_poolb_final(const float* poolp, const int* start,
                                                     const float* W_out, const float* b_out,
                                                     float* out){
  __shared__ float pl[DH];
  int g = blockIdx.x, c = threadIdx.x;
  int cntg = start[g + 1] - start[g]; if (cntg < 1) cntg = 1;
  pl[c] = poolp[g * DO + c] / (float)cntg;
  __syncthreads();
  float acc = b_out[c];
  for (int k = 0; k < DH; ++k) acc += pl[k] * W_out[k * DO + c];
  out[g * DO + c] = acc;
}

extern "C" void kernel_launch(void* const* d_in, const int* in_sizes, int n_in,
                              void* d_out, int out_size, void* d_ws, size_t ws_size,
                              hipStream_t stream){
  const float* x         = (const float*)d_in[0];
  const int*   edge_index= (const int*)  d_in[1];
  const float* edge_attr = (const float*)d_in[2];
  const int*   batch     = (const int*)  d_in[3];
  const float* W_gcn     = (const float*)d_in[4];
  const float* b_gcn     = (const float*)d_in[5];
  const float* W_le      = (const float*)d_in[6];
  const float* b_le      = (const float*)d_in[7];
  const float* W_lin     = (const float*)d_in[8];
  const float* b_lin     = (const float*)d_in[9];
  const float* W_out     = (const float*)d_in[10];
  const float* b_out     = (const float*)d_in[11];
  float* out = (float*)d_out;

  const int n  = in_sizes[0] / DV;       // 100000
  const int e2 = in_sizes[1] / 2;        // 1600000 directed edges
  const int g  = out_size / DO;          // 64
  const int* srcp = edge_index;
  const int* dstp = edge_index + e2;
  const int e2pad = e2 + 7 * n + 8;      // CSR capacity with per-row pad-to-8

  char* ws = (char*)d_ws;
  size_t off = 0;
  auto alloc = [&](size_t bytes) -> char* {
    char* p = ws + off; off = (off + bytes + 255) & ~(size_t)255; return p;
  };

  int*   cnt     = (int*)  alloc((size_t)n * 4);
  int*   row_ptr = (int*)  alloc((size_t)(n + 1) * 4);
  int*   rank    = (int*)  alloc((size_t)e2 * 4);
  int*   partial = (int*)  alloc((size_t)n * 4);
  int*   bsums   = (int*)  alloc(512);
  float* dinv    = (float*)alloc((size_t)n * 4);
  float* degf    = (float*)alloc((size_t)n * 4);
  int*   startg  = (int*)  alloc((size_t)(g + 1) * 4);
  float* poolp   = (float*)alloc((size_t)g * DO * 4);
  float* Wfull   = (float*)alloc(160 * DH * 4);
  u32*   h8      = (u32*)  alloc((size_t)(n + 1) * 128);   // fp8 rows, +1 zero row
  int2*  ce      = (int2*) alloc((size_t)e2pad * 8);
  u32*   ea_bf   = (u32*)  alloc((size_t)e2 * 16);         // bf16 ea table
  u32*   xws8    = (u32*)  alloc((size_t)(n + 1) * 128);   // fp8 rows, +1 zero row

  const int nb1024 = (n + 1023) / 1024;  // must be <= 128 for the inline scan
  const int NB = (n + 255) / 256;        // scan3w: node blocks, then 80 wcombo blocks
  const int SB = (e2 + 255) / 256;       // scatter blocks in the fused scatter+gemm1
  const int GB = (n + 63) / 64;          // gemm1 / p2gemm blocks

  k_init      <<<(n + 255) / 256, 256, 0, stream>>>(cnt, poolp,
                                                    xws8 + (size_t)n * 32, h8 + (size_t)n * 32,
                                                    n, g * DO);
  k_count     <<<SB, 256, 0, stream>>>(dstp, edge_attr, cnt, rank, ea_bf, ce,
                                       e2, e2pad, n << 5);
  k_scan1     <<<nb1024, 256, 0, stream>>>(cnt, partial, bsums, n);
  k_scan3w    <<<NB + 80, 256, 0, stream>>>(partial, bsums, nb1024, row_ptr, cnt, dinv, degf,
                                            batch, startg, n, g, NB,
                                            W_lin, b_lin, W_le, b_le, Wfull);
  k_scatter_g1<<<SB + GB, 256, 0, stream>>>(srcp, dstp, rank, row_ptr, ce, e2, SB,
                                            x, W_gcn, dinv, xws8, n);
  k_phase1    <<<(n + 7) / 8, 256, 0, stream>>>(xws8, row_ptr, ce, dinv, b_gcn, h8, n);
  k_p2gemm    <<<GB, 256, 0, stream>>>(h8, row_ptr, ce, (const u16*)ea_bf, degf,
                                       Wfull, n, batch, poolp);
  k_poolb_final<<<g, 128, 0, stream>>>(poolp, startg, W_out, b_out, out);
}

// Round 12
// 382.488 us; speedup vs baseline: 1.0689x; 1.0689x over previous
//
#include <hip/hip_runtime.h>
#include <hip/hip_bf16.h>
#include <cstddef>

typedef unsigned int  u32;
typedef unsigned short u16;
typedef __attribute__((ext_vector_type(8))) short short8;
typedef __attribute__((ext_vector_type(4))) float f32x4;
typedef __attribute__((ext_vector_type(2))) float f32x2;

#define DV 128
#define DH 128
#define DE 16
#define DO 128

// ---------- bf16 helpers (bit tricks, RNE) ----------
__device__ inline float bf_lo(u32 u){ return __uint_as_float(u << 16); }
__device__ inline float bf_hi(u32 u){ return __uint_as_float(u & 0xFFFF0000u); }
__device__ inline u32 fpack2(float a, float b){
  u32 ua = __float_as_uint(a), ub = __float_as_uint(b);
  ua += 0x7FFFu + ((ua >> 16) & 1u);
  ub += 0x7FFFu + ((ub >> 16) & 1u);
  return (ua >> 16) | (ub & 0xFFFF0000u);
}
__device__ inline u16 f2bf(float a){
  u32 ua = __float_as_uint(a); ua += 0x7FFFu + ((ua >> 16) & 1u); return (u16)(ua >> 16);
}

// ---------- fp8 (OCP e4m3) helpers: 4 channels per u32 ----------
__device__ inline void acc_fp8v(u32 s, f32x2& lo, f32x2& hi){
  lo += __builtin_amdgcn_cvt_pk_f32_fp8((int)s, false);
  hi += __builtin_amdgcn_cvt_pk_f32_fp8((int)s, true);
}
__device__ inline u32 pack_fp8(float a0, float a1, float a2, float a3){
  int o = __builtin_amdgcn_cvt_pk_fp8_f32(a0, a1, 0, false);
  o = __builtin_amdgcn_cvt_pk_fp8_f32(a2, a3, o, true);
  return (u32)o;
}

// ---------- init: zero cnt/poolp/zrows (ce prefill rides under k_count) ----------
__global__ void k_init(int* cnt, float* poolp, u32* xws_zrow, u32* h_zrow, int n, int pn){
  int v = blockIdx.x * blockDim.x + threadIdx.x;
  if (v < n) cnt[v] = 0;
  if (v < pn) poolp[v] = 0.f;
  if (v < 32){ xws_zrow[v] = 0u; h_zrow[v] = 0u; }
}

// count + per-edge rank (atomic-throughput-bound, ~68us floor). Streaming riders
// nearly free under the atomic latency (r2/r3 A/B): ea->bf16 table, ce pad-prefill.
__global__ void k_count(const int* dst, const float* edge_attr, int* cnt, int* rank,
                        u32* ea_pack, int2* ce, int e2, int cefill, int nmark){
  int j = blockIdx.x * blockDim.x + threadIdx.x;
  int tot = gridDim.x * blockDim.x;
  if (j < e2){
    rank[j] = atomicAdd(&cnt[dst[j]], 1);
    float4 f0 = *(const float4*)(edge_attr + (size_t)j * 8);
    float4 f1 = *(const float4*)(edge_attr + (size_t)j * 8 + 4);
    uint4 o;
    o.x = fpack2(f0.x, f0.y); o.y = fpack2(f0.z, f0.w);
    o.z = fpack2(f1.x, f1.y); o.w = fpack2(f1.z, f1.w);
    *(uint4*)(ea_pack + (size_t)j * 4) = o;
  }
  int2 pd = make_int2(nmark, 0);
  for (int i = j; i < cefill; i += tot) ce[i] = pd;
}

// scan of PADDED counts: pc = (cnt+7)&~7
__global__ __launch_bounds__(256) void k_scan1(const int* cnt, int* partial, int* bsums, int n){
  __shared__ int lds[256];
  int t = threadIdx.x;
  int base = blockIdx.x * 1024 + t * 4;
  int v0=0,v1=0,v2=0,v3=0;
  if (base + 3 < n){ int4 q = *(const int4*)(cnt + base); v0=q.x; v1=q.y; v2=q.z; v3=q.w; }
  else {
    if (base + 0 < n) v0 = cnt[base];
    if (base + 1 < n) v1 = cnt[base+1];
    if (base + 2 < n) v2 = cnt[base+2];
  }
  v0 = (v0 + 7) & ~7; v1 = (v1 + 7) & ~7; v2 = (v2 + 7) & ~7; v3 = (v3 + 7) & ~7;
  v1 += v0; v2 += v1; v3 += v2;
  lds[t] = v3; __syncthreads();
  for (int off = 1; off < 256; off <<= 1){
    int x = (t >= off) ? lds[t - off] : 0;
    __syncthreads();
    lds[t] += x;
    __syncthreads();
  }
  int add = (t > 0) ? lds[t - 1] : 0;
  if (base + 3 < n){
    int4 q; q.x = v0+add; q.y = v1+add; q.z = v2+add; q.w = v3+add;
    *(int4*)(partial + base) = q;
  } else {
    if (base + 0 < n) partial[base]   = v0 + add;
    if (base + 1 < n) partial[base+1] = v1 + add;
    if (base + 2 < n) partial[base+2] = v2 + add;
  }
  if (t == 255) bsums[blockIdx.x] = lds[255];
}

// fused: (a) blocks [0,NB): inline bsums scan + row_ptr + dinv/degf + graph starts;
// (b) blocks [NB,NB+80): wcombo weight fold (fp32 Wfull).
__global__ __launch_bounds__(256) void k_scan3w(const int* partial, const int* bsums, int nb,
                                                int* row_ptr, const int* cnt,
                                                float* dinv, float* degf,
                                                const int* batch, int* startg, int n, int g, int NB,
                                                const float* W_lin, const float* b_lin,
                                                const float* W_le, const float* b_le, float* Wfull){
  int bid = blockIdx.x;
  int t = threadIdx.x;
  if (bid >= NB){
    int r = (bid - NB) * 2 + (t >> 7), c = t & 127;
    if (r < DH){
      Wfull[r * DH + c] = W_lin[r * DH + c];
    } else if (r < DH + DE){
      int i = r - DH;
      float acc = 0.f;
      #pragma unroll 8
      for (int k = 0; k < DH; k += 4){
        float4 wl = *(const float4*)(W_le + i * DH + k);
        acc += wl.x * W_lin[(size_t)(DH + k    ) * DH + c];
        acc += wl.y * W_lin[(size_t)(DH + k + 1) * DH + c];
        acc += wl.z * W_lin[(size_t)(DH + k + 2) * DH + c];
        acc += wl.w * W_lin[(size_t)(DH + k + 3) * DH + c];
      }
      Wfull[r * DH + c] = acc;
    } else if (r == 144){
      float acc = b_lin[c];
      #pragma unroll 8
      for (int k = 0; k < DH; k += 4){
        float4 bl = *(const float4*)(b_le + k);
        acc += bl.x * W_lin[(size_t)(DH + k    ) * DH + c];
        acc += bl.y * W_lin[(size_t)(DH + k + 1) * DH + c];
        acc += bl.z * W_lin[(size_t)(DH + k + 2) * DH + c];
        acc += bl.w * W_lin[(size_t)(DH + k + 3) * DH + c];
      }
      Wfull[r * DH + c] = acc;
    } else if (r < 160){
      Wfull[r * DH + c] = 0.f;
    }
    return;
  }
  __shared__ int lds[128];
  if (t < 128) lds[t] = (t < nb) ? bsums[t] : 0;
  __syncthreads();
  for (int off = 1; off < 128; off <<= 1){
    int x = (t >= off && t < 128) ? lds[t - off] : 0;
    __syncthreads();
    if (t < 128) lds[t] += x;
    __syncthreads();
  }
  int i = bid * 256 + t;
  if (i < n){
    int chunk = i >> 10;
    int add = (chunk > 0) ? lds[chunk - 1] : 0;
    row_ptr[i + 1] = partial[i] + add;
    if (i == 0) row_ptr[0] = 0;
    float c = (float)(cnt[i] + 1);
    dinv[i] = rsqrtf(c);
    degf[i] = c;
    int b = batch[i];
    int prev = (i == 0) ? -1 : batch[i - 1];
    for (int q = prev + 1; q <= b; ++q) startg[q] = i;
    if (i == n - 1){ for (int q = b + 1; q <= g; ++q) startg[q] = n; }
  }
}

// ---------- fused scatter + gemm1 (r5->r6 proved gemm1 hides under scatter) ----------
__global__ __launch_bounds__(256) void k_scatter_g1(const int* src, const int* dst, const int* rank,
                                                    const int* row_ptr, int2* ce, int e2, int SB,
                                                    const float* x, const float* W,
                                                    const float* dinv, u32* xws8, int M){
  __shared__ u16 lds_u[64 * 136];   // 17408 B
  int bid = blockIdx.x;
  int tid = threadIdx.x;
  if (bid < SB){
    int j = bid * 256 + tid;
    if (j < e2){
      int d = dst[j];
      int pos = row_ptr[d] + rank[j];
      ce[pos] = make_int2(src[j] << 5, j >> 1);
    }
    return;
  }
  int row0 = (bid - SB) * 64;
  u16* Wt = lds_u;              // per-slice [128][40]
  u16* At = lds_u + 128 * 40;   // per-slice [64][40]
  int l = tid & 63, w = tid >> 6;
  int m = l & 15, quad = l >> 4;
  f32x4 acc[8];
  #pragma unroll
  for (int ct = 0; ct < 8; ++ct) acc[ct] = (f32x4){0.f, 0.f, 0.f, 0.f};
  for (int ks = 0; ks < DV; ks += 32){
    __syncthreads();
    {
      int c = tid & 127, hh = tid >> 7;
      #pragma unroll
      for (int g2 = 0; g2 < 2; ++g2){
        int k0 = hh * 16 + g2 * 8;
        const float* Wp = W + (size_t)(ks + k0) * 128 + c;
        float w0 = Wp[0*128], w1 = Wp[1*128], w2 = Wp[2*128], w3 = Wp[3*128];
        float w4 = Wp[4*128], w5 = Wp[5*128], w6 = Wp[6*128], w7 = Wp[7*128];
        uint4 pk;
        pk.x = fpack2(w0, w1); pk.y = fpack2(w2, w3);
        pk.z = fpack2(w4, w5); pk.w = fpack2(w6, w7);
        *(uint4*)&Wt[c * 40 + k0] = pk;
      }
    }
    {
      int r = tid >> 2, ch = tid & 3;
      int gr = row0 + r; if (gr > M - 1) gr = M - 1;
      const float* A = x + (size_t)gr * DV + ks + ch * 8;
      float4 q0 = *(const float4*)A;
      float4 q1 = *(const float4*)(A + 4);
      uint4 pk;
      pk.x = fpack2(q0.x, q0.y); pk.y = fpack2(q0.z, q0.w);
      pk.z = fpack2(q1.x, q1.y); pk.w = fpack2(q1.z, q1.w);
      *(uint4*)&At[r * 40 + ch * 8] = pk;
    }
    __syncthreads();
    short8 av = *(const short8*)&At[(w * 16 + m) * 40 + quad * 8];
    #pragma unroll
    for (int ct = 0; ct < 8; ++ct){
      short8 bv = *(const short8*)&Wt[(ct * 16 + m) * 40 + quad * 8];
      acc[ct] = __builtin_amdgcn_mfma_f32_16x16x32_bf16(av, bv, acc[ct], 0, 0, 0);
    }
  }
  __syncthreads();
  u16* Ct = lds_u;
  float sc[4];
  #pragma unroll
  for (int r = 0; r < 4; ++r){
    int gr = row0 + w * 16 + quad * 4 + r;
    sc[r] = dinv[gr < M ? gr : (M - 1)];
  }
  #pragma unroll
  for (int ct = 0; ct < 8; ++ct){
    #pragma unroll
    for (int r = 0; r < 4; ++r){
      float vv = acc[ct][r] * sc[r];
      Ct[(w * 16 + quad * 4 + r) * 136 + ct * 16 + m] = f2bf(vv);
    }
  }
  __syncthreads();
  for (int idx = tid; idx < 64 * 16; idx += 256){
    int r = idx >> 4, c8 = idx & 15;
    int gr = row0 + r;
    if (gr < M){
      uint4 qv = *(const uint4*)&Ct[r * 136 + c8 * 8];
      uint2 ov;
      ov.x = (u32)__builtin_amdgcn_cvt_pk_fp8_f32(bf_lo(qv.y), bf_hi(qv.y),
             __builtin_amdgcn_cvt_pk_fp8_f32(bf_lo(qv.x), bf_hi(qv.x), 0, false), true);
      ov.y = (u32)__builtin_amdgcn_cvt_pk_fp8_f32(bf_lo(qv.w), bf_hi(qv.w),
             __builtin_amdgcn_cvt_pk_fp8_f32(bf_lo(qv.z), bf_hi(qv.z), 0, false), true);
      *(uint2*)(xws8 + (size_t)gr * 32 + c8 * 2) = ov;
    }
  }
}

// ---------- phase 1: fp8 table, 2 nodes/wave, depth-2 pipeline ----------
__global__ __launch_bounds__(256) void k_phase1(const u32* xws8, const int* row_ptr, const int2* ce,
                                                const float* dinv, const float* b_gcn, u32* h8, int n){
  int lane = threadIdx.x & 63;
  int ln = lane & 31;
  int v = blockIdx.x * 8 + ((threadIdx.x >> 6) << 1) + (lane >> 5);
  if (v >= n) return;
  u32 sp = xws8[(size_t)v * 32 + ln];
  f32x2 aLo = (f32x2){0.f, 0.f}, aHi = (f32x2){0.f, 0.f};
  acc_fp8v(sp, aLo, aHi);
  int e0 = row_ptr[v], e1 = row_ptr[v + 1];
  int B = (e1 - e0) >> 3;
  const int4* cp = (const int4*)(ce + e0);
  u32 q0=0,q1=0,q2=0,q3=0,q4=0,q5=0,q6=0,q7=0;
  u32 r0=0,r1=0,r2=0,r3=0,r4=0,r5=0,r6=0,r7=0;
  if (B > 0){
    int4 A = cp[0], Bb = cp[1], C = cp[2], D = cp[3];
    q0 = xws8[A.x + ln]; q1 = xws8[A.z + ln];
    q2 = xws8[Bb.x + ln]; q3 = xws8[Bb.z + ln];
    q4 = xws8[C.x + ln]; q5 = xws8[C.z + ln];
    q6 = xws8[D.x + ln]; q7 = xws8[D.z + ln];
  }
  if (B > 1){
    int4 A = cp[4], Bb = cp[5], C = cp[6], D = cp[7];
    r0 = xws8[A.x + ln]; r1 = xws8[A.z + ln];
    r2 = xws8[Bb.x + ln]; r3 = xws8[Bb.z + ln];
    r4 = xws8[C.x + ln]; r5 = xws8[C.z + ln];
    r6 = xws8[D.x + ln]; r7 = xws8[D.z + ln];
  }
  for (int k = 0; k + 2 < B; ++k){
    const int4* cpp = cp + (size_t)(k + 2) * 4;
    int4 A = cpp[0], Bb = cpp[1], C = cpp[2], D = cpp[3];
    u32 p0 = xws8[A.x + ln], p1 = xws8[A.z + ln];
    u32 p2 = xws8[Bb.x + ln], p3 = xws8[Bb.z + ln];
    u32 p4 = xws8[C.x + ln], p5 = xws8[C.z + ln];
    u32 p6 = xws8[D.x + ln], p7 = xws8[D.z + ln];
    acc_fp8v(q0, aLo, aHi); acc_fp8v(q1, aLo, aHi);
    acc_fp8v(q2, aLo, aHi); acc_fp8v(q3, aLo, aHi);
    acc_fp8v(q4, aLo, aHi); acc_fp8v(q5, aLo, aHi);
    acc_fp8v(q6, aLo, aHi); acc_fp8v(q7, aLo, aHi);
    q0=r0; q1=r1; q2=r2; q3=r3; q4=r4; q5=r5; q6=r6; q7=r7;
    r0=p0; r1=p1; r2=p2; r3=p3; r4=p4; r5=p5; r6=p6; r7=p7;
  }
  if (B > 1){
    acc_fp8v(q0, aLo, aHi); acc_fp8v(q1, aLo, aHi);
    acc_fp8v(q2, aLo, aHi); acc_fp8v(q3, aLo, aHi);
    acc_fp8v(q4, aLo, aHi); acc_fp8v(q5, aLo, aHi);
    acc_fp8v(q6, aLo, aHi); acc_fp8v(q7, aLo, aHi);
    q0=r0; q1=r1; q2=r2; q3=r3; q4=r4; q5=r5; q6=r6; q7=r7;
  }
  if (B > 0){
    acc_fp8v(q0, aLo, aHi); acc_fp8v(q1, aLo, aHi);
    acc_fp8v(q2, aLo, aHi); acc_fp8v(q3, aLo, aHi);
    acc_fp8v(q4, aLo, aHi); acc_fp8v(q5, aLo, aHi);
    acc_fp8v(q6, aLo, aHi); acc_fp8v(q7, aLo, aHi);
  }
  float dv = dinv[v];
  float4 bg = *(const float4*)(b_gcn + ln * 4);
  float a0 = fmaxf(fmaf(dv, aLo.x, bg.x), 0.f);
  float a1 = fmaxf(fmaf(dv, aLo.y, bg.y), 0.f);
  float a2 = fmaxf(fmaf(dv, aHi.x, bg.z), 0.f);
  float a3 = fmaxf(fmaf(dv, aHi.y, bg.w), 0.f);
  h8[(size_t)v * 32 + ln] = pack_fp8(a0, a1, a2, a3);
}

// ---------- FUSED phase2 + gemm2 + pool, 8-WAVE blocks ----------
// r10 (less LDS) and r11 (depth-2) both nulled: the binder is resident BLOCKS,
// not LDS or per-wave MLP. 512 threads/block doubles gather waves per resident
// block: 8 waves build the 64-row A2 tile (4 passes x 16 nodes, depth-1 r9
// math), then 8-wave gemm (wave = 16-row block x 64-col half, acc[4]; same
// slice/fragment order -> bit-identical) + pool epilogue.
__global__ __launch_bounds__(512) void k_p2gemm(const u32* h8, const int* row_ptr, const int2* ce,
                                                const u16* ea_bf, const float* degf,
                                                const float* W, int n,
                                                const int* batchp, float* poolp){
  __shared__ u16 At2[64 * 174];      // full A2 tile (22272 B)
  __shared__ u16 Wt[128 * 40];       // per-slice W (10240 B); pool scratch later
  int tid = threadIdx.x;
  int lane = tid & 63;
  int ln = lane & 31;
  int half = lane >> 5;
  int wv = tid >> 6;                 // 0..7
  int row0 = blockIdx.x * 64;
  int ch = ln & 15, grp = ln >> 4;
  int nmark = n << 5;

  // ---- 4 passes x 16 nodes: build A2 rows in LDS (r9 depth-1 math) ----
  for (int pass = 0; pass < 4; ++pass){
    int local = pass * 16 + wv * 2 + half;
    int v = row0 + local;
    u32* rowp = (u32*)&At2[(size_t)local * 174];
    if (v >= n){
      rowp[ln] = 0u; rowp[ln + 32] = 0u;
      if (ln < 16) rowp[ln + 64] = 0u;
      continue;
    }
    u32 sp = h8[(size_t)v * 32 + ln];
    f32x2 aLo = (f32x2){0.f, 0.f}, aHi = (f32x2){0.f, 0.f};
    acc_fp8v(sp, aLo, aHi);
    float es = 0.f;
    int e0 = row_ptr[v], e1 = row_ptr[v + 1];
    int i = e0;
    u32 q0=0,q1=0,q2=0,q3=0,q4=0,q5=0,q6=0,q7=0;
    float w0=0.f,w1=0.f,w2=0.f,w3=0.f;
    float m0=0.f,m1=0.f,m2=0.f,m3=0.f;
    if (i < e1){
      const int4* cp = (const int4*)(ce + i);
      int4 A = cp[0], B = cp[1], C = cp[2], D = cp[3];
      q0 = h8[A.x + ln]; q1 = h8[A.z + ln];
      q2 = h8[B.x + ln]; q3 = h8[B.z + ln];
      q4 = h8[C.x + ln]; q5 = h8[C.z + ln];
      q6 = h8[D.x + ln]; q7 = h8[D.z + ln];
      int s0x = grp ? C.x : A.x, s0e = grp ? C.y : A.y;
      int s1x = grp ? C.z : A.z, s1e = grp ? C.w : A.w;
      int s2x = grp ? D.x : B.x, s2e = grp ? D.y : B.y;
      int s3x = grp ? D.z : B.z, s3e = grp ? D.w : B.w;
      w0 = bf_lo((u32)ea_bf[(size_t)s0e * 16 + ch]);
      w1 = bf_lo((u32)ea_bf[(size_t)s1e * 16 + ch]);
      w2 = bf_lo((u32)ea_bf[(size_t)s2e * 16 + ch]);
      w3 = bf_lo((u32)ea_bf[(size_t)s3e * 16 + ch]);
      m0 = (s0x != nmark) ? 1.f : 0.f;
      m1 = (s1x != nmark) ? 1.f : 0.f;
      m2 = (s2x != nmark) ? 1.f : 0.f;
      m3 = (s3x != nmark) ? 1.f : 0.f;
    }
    for (; i + 8 < e1; i += 8){
      const int4* cp2 = (const int4*)(ce + i + 8);
      int4 A2 = cp2[0], B2 = cp2[1], C2 = cp2[2], D2 = cp2[3];
      int t0x = grp ? C2.x : A2.x, t0e = grp ? C2.y : A2.y;
      int t1x = grp ? C2.z : A2.z, t1e = grp ? C2.w : A2.w;
      int t2x = grp ? D2.x : B2.x, t2e = grp ? D2.y : B2.y;
      int t3x = grp ? D2.z : B2.z, t3e = grp ? D2.w : B2.w;
      float u0 = bf_lo((u32)ea_bf[(size_t)t0e * 16 + ch]);
      float u1 = bf_lo((u32)ea_bf[(size_t)t1e * 16 + ch]);
      float u2 = bf_lo((u32)ea_bf[(size_t)t2e * 16 + ch]);
      float u3 = bf_lo((u32)ea_bf[(size_t)t3e * 16 + ch]);
      float n0 = (t0x != nmark) ? 1.f : 0.f;
      float n1 = (t1x != nmark) ? 1.f : 0.f;
      float n2 = (t2x != nmark) ? 1.f : 0.f;
      float n3 = (t3x != nmark) ? 1.f : 0.f;
      u32 p0 = h8[A2.x + ln], p1 = h8[A2.z + ln];
      u32 p2 = h8[B2.x + ln], p3 = h8[B2.z + ln];
      u32 p4 = h8[C2.x + ln], p5 = h8[C2.z + ln];
      u32 p6 = h8[D2.x + ln], p7 = h8[D2.z + ln];
      acc_fp8v(q0, aLo, aHi); acc_fp8v(q1, aLo, aHi);
      acc_fp8v(q2, aLo, aHi); acc_fp8v(q3, aLo, aHi);
      acc_fp8v(q4, aLo, aHi); acc_fp8v(q5, aLo, aHi);
      acc_fp8v(q6, aLo, aHi); acc_fp8v(q7, aLo, aHi);
      es = fmaf(m0, w0, es);
      es = fmaf(m1, w1, es);
      es = fmaf(m2, w2, es);
      es = fmaf(m3, w3, es);
      q0=p0; q1=p1; q2=p2; q3=p3; q4=p4; q5=p5; q6=p6; q7=p7;
      w0=u0; w1=u1; w2=u2; w3=u3;
      m0=n0; m1=n1; m2=n2; m3=n3;
    }
    if (i < e1){
      acc_fp8v(q0, aLo, aHi); acc_fp8v(q1, aLo, aHi);
      acc_fp8v(q2, aLo, aHi); acc_fp8v(q3, aLo, aHi);
      acc_fp8v(q4, aLo, aHi); acc_fp8v(q5, aLo, aHi);
      acc_fp8v(q6, aLo, aHi); acc_fp8v(q7, aLo, aHi);
      es = fmaf(m0, w0, es);
      es = fmaf(m1, w1, es);
      es = fmaf(m2, w2, es);
      es = fmaf(m3, w3, es);
    }
    es += __shfl_xor(es, 16);
    float c0v = __shfl(es, half * 32 + (ln & 7) * 2);
    float c1v = __shfl(es, half * 32 + (ln & 7) * 2 + 1);
    uint2 o; o.x = fpack2(aLo.x, aLo.y); o.y = fpack2(aHi.x, aHi.y);
    *(uint2*)(rowp + ln * 2) = o;
    if (ln < 8){
      rowp[64 + ln] = fpack2(c0v + 1.0f, c1v + 1.0f);
    } else if (ln < 16){
      rowp[64 + ln] = (ln == 8) ? (u32)f2bf(degf[v]) : 0u;
    }
  }
  __syncthreads();

  // ---- gemm: 8 waves, wave = rows (wv&3)*16.. x cols (wv>>2)*64.. ----
  int m = lane & 15, quad = lane >> 4;
  int rw = wv & 3, chf = wv >> 2;
  f32x4 acc[4];
  #pragma unroll
  for (int ct = 0; ct < 4; ++ct) acc[ct] = (f32x4){0.f, 0.f, 0.f, 0.f};
  for (int ks = 0; ks < 160; ks += 32){
    __syncthreads();   // previous slice's Wt fully consumed
    {  // stage Wt slice: 512 threads, one uint4 store each
      int c = tid & 127, hh = tid >> 7;    // hh in 0..3
      int k0 = hh * 8;
      const float* Wp = W + (size_t)(ks + k0) * 128 + c;
      float w0 = Wp[0*128], w1 = Wp[1*128], w2 = Wp[2*128], w3 = Wp[3*128];
      float w4 = Wp[4*128], w5 = Wp[5*128], w6 = Wp[6*128], w7 = Wp[7*128];
      uint4 pk;
      pk.x = fpack2(w0, w1); pk.y = fpack2(w2, w3);
      pk.z = fpack2(w4, w5); pk.w = fpack2(w6, w7);
      *(uint4*)&Wt[c * 40 + k0] = pk;
    }
    __syncthreads();
    short8 av = *(const short8*)&At2[(rw * 16 + m) * 174 + ks + quad * 8];
    #pragma unroll
    for (int ct = 0; ct < 4; ++ct){
      short8 bv = *(const short8*)&Wt[(chf * 64 + ct * 16 + m) * 40 + quad * 8];
      acc[ct] = __builtin_amdgcn_mfma_f32_16x16x32_bf16(av, bv, acc[ct], 0, 0, 0);
    }
  }
  __syncthreads();   // done with Wt — reuse as pool scratch

  // ---- fused mean-pool epilogue (same reduction; each (rowblk,col) once) ----
  float* ps = (float*)Wt;
  int rbase = rw * 16 + quad * 4;
  int g0 = batchp[row0];
  int glast = batchp[(row0 + 63 < n) ? (row0 + 63) : (n - 1)];
  if (g0 == glast){
    #pragma unroll
    for (int ct = 0; ct < 4; ++ct){
      float s = 0.f;
      #pragma unroll
      for (int r = 0; r < 4; ++r){
        float vv = fmaxf(acc[ct][r], 0.f);
        if (row0 + rbase + r < n) s += vv;
      }
      s += __shfl_xor(s, 16);
      s += __shfl_xor(s, 32);
      if (quad == 0) ps[rw * 128 + chf * 64 + ct * 16 + m] = s;
    }
    __syncthreads();
    if (tid < 128){
      float t = ps[tid] + ps[128 + tid] + ps[256 + tid] + ps[384 + tid];
      atomicAdd(&poolp[g0 * DO + tid], t);
    }
  } else {
    #pragma unroll
    for (int ct = 0; ct < 4; ++ct){
      #pragma unroll
      for (int r = 0; r < 4; ++r){
        int row = row0 + rbase + r;
        if (row < n){
          float vv = fmaxf(acc[ct][r], 0.f);
          atomicAdd(&poolp[batchp[row] * DO + chf * 64 + ct * 16 + m], vv);
        }
      }
    }
  }
}

// ---------- final: mean + linear ----------
__global__ __launch_bounds__(128) void k_poolb_final(const float* poolp, const int* start,
                                                     const float* W_out, const float* b_out,
                                                     float* out){
  __shared__ float pl[DH];
  int g = blockIdx.x, c = threadIdx.x;
  int cntg = start[g + 1] - start[g]; if (cntg < 1) cntg = 1;
  pl[c] = poolp[g * DO + c] / (float)cntg;
  __syncthreads();
  float acc = b_out[c];
  for (int k = 0; k < DH; ++k) acc += pl[k] * W_out[k * DO + c];
  out[g * DO + c] = acc;
}

extern "C" void kernel_launch(void* const* d_in, const int* in_sizes, int n_in,
                              void* d_out, int out_size, void* d_ws, size_t ws_size,
                              hipStream_t stream){
  const float* x         = (const float*)d_in[0];
  const int*   edge_index= (const int*)  d_in[1];
  const float* edge_attr = (const float*)d_in[2];
  const int*   batch     = (const int*)  d_in[3];
  const float* W_gcn     = (const float*)d_in[4];
  const float* b_gcn     = (const float*)d_in[5];
  const float* W_le      = (const float*)d_in[6];
  const float* b_le      = (const float*)d_in[7];
  const float* W_lin     = (const float*)d_in[8];
  const float* b_lin     = (const float*)d_in[9];
  const float* W_out     = (const float*)d_in[10];
  const float* b_out     = (const float*)d_in[11];
  float* out = (float*)d_out;

  const int n  = in_sizes[0] / DV;       // 100000
  const int e2 = in_sizes[1] / 2;        // 1600000 directed edges
  const int g  = out_size / DO;          // 64
  const int* srcp = edge_index;
  const int* dstp = edge_index + e2;
  const int e2pad = e2 + 7 * n + 8;      // CSR capacity with per-row pad-to-8

  char* ws = (char*)d_ws;
  size_t off = 0;
  auto alloc = [&](size_t bytes) -> char* {
    char* p = ws + off; off = (off + bytes + 255) & ~(size_t)255; return p;
  };

  int*   cnt     = (int*)  alloc((size_t)n * 4);
  int*   row_ptr = (int*)  alloc((size_t)(n + 1) * 4);
  int*   rank    = (int*)  alloc((size_t)e2 * 4);
  int*   partial = (int*)  alloc((size_t)n * 4);
  int*   bsums   = (int*)  alloc(512);
  float* dinv    = (float*)alloc((size_t)n * 4);
  float* degf    = (float*)alloc((size_t)n * 4);
  int*   startg  = (int*)  alloc((size_t)(g + 1) * 4);
  float* poolp   = (float*)alloc((size_t)g * DO * 4);
  float* Wfull   = (float*)alloc(160 * DH * 4);
  u32*   h8      = (u32*)  alloc((size_t)(n + 1) * 128);   // fp8 rows, +1 zero row
  int2*  ce      = (int2*) alloc((size_t)e2pad * 8);
  u32*   ea_bf   = (u32*)  alloc((size_t)e2 * 16);         // bf16 ea table
  u32*   xws8    = (u32*)  alloc((size_t)(n + 1) * 128);   // fp8 rows, +1 zero row

  const int nb1024 = (n + 1023) / 1024;  // must be <= 128 for the inline scan
  const int NB = (n + 255) / 256;        // scan3w: node blocks, then 80 wcombo blocks
  const int SB = (e2 + 255) / 256;       // scatter blocks in the fused scatter+gemm1
  const int GB = (n + 63) / 64;          // gemm1 / p2gemm blocks

  k_init      <<<(n + 255) / 256, 256, 0, stream>>>(cnt, poolp,
                                                    xws8 + (size_t)n * 32, h8 + (size_t)n * 32,
                                                    n, g * DO);
  k_count     <<<SB, 256, 0, stream>>>(dstp, edge_attr, cnt, rank, ea_bf, ce,
                                       e2, e2pad, n << 5);
  k_scan1     <<<nb1024, 256, 0, stream>>>(cnt, partial, bsums, n);
  k_scan3w    <<<NB + 80, 256, 0, stream>>>(partial, bsums, nb1024, row_ptr, cnt, dinv, degf,
                                            batch, startg, n, g, NB,
                                            W_lin, b_lin, W_le, b_le, Wfull);
  k_scatter_g1<<<SB + GB, 256, 0, stream>>>(srcp, dstp, rank, row_ptr, ce, e2, SB,
                                            x, W_gcn, dinv, xws8, n);
  k_phase1    <<<(n + 7) / 8, 256, 0, stream>>>(xws8, row_ptr, ce, dinv, b_gcn, h8, n);
  k_p2gemm    <<<GB, 512, 0, stream>>>(h8, row_ptr, ce, (const u16*)ea_bf, degf,
                                       Wfull, n, batch, poolp);
  k_poolb_final<<<g, 128, 0, stream>>>(poolp, startg, W_out, b_out, out);
}